// Round 1
// baseline (2999.814 us; speedup 1.0000x reference)
//
#include <hip/hip_runtime.h>
#include <hip/hip_bf16.h>
#include <math.h>

#define NTOK 2048
#define HID 2048
#define FFN 5632
#define NEXP 8

typedef __attribute__((ext_vector_type(8))) short bf16x8;
typedef __attribute__((ext_vector_type(4))) float f32x4;

__device__ __forceinline__ unsigned short f2bf(float f) {
    union { float f; unsigned u; } v; v.f = f;
    unsigned r = v.u + 0x7fffu + ((v.u >> 16) & 1u);
    return (unsigned short)(r >> 16);
}

// ---------------- zero out + counts (capture-safe, no memset) ----------------
__global__ void zero_kernel(float4* __restrict__ out, int n4, int* __restrict__ counts) {
    int i = blockIdx.x * 256 + threadIdx.x;
    if (i < n4) out[i] = make_float4(0.f, 0.f, 0.f, 0.f);
    if (i < NEXP) counts[i] = 0;
}

// ---------------- router: logits, top-2, renorm weights, build lists --------
__global__ void router_kernel(const float* __restrict__ x, const float* __restrict__ wg,
                              int* __restrict__ counts, int* __restrict__ rowids,
                              float* __restrict__ rweights) {
    int t = blockIdx.x;
    const float* xr = x + (size_t)t * HID;
    float acc[NEXP];
#pragma unroll
    for (int e = 0; e < NEXP; e++) acc[e] = 0.f;
    for (int j = threadIdx.x; j < HID; j += 256) {
        float xv = xr[j];
#pragma unroll
        for (int e = 0; e < NEXP; e++) acc[e] += xv * wg[e * HID + j];
    }
    // wave reduce (64 lanes)
#pragma unroll
    for (int e = 0; e < NEXP; e++) {
        float v = acc[e];
        for (int off = 32; off > 0; off >>= 1) v += __shfl_down(v, off, 64);
        acc[e] = v;
    }
    __shared__ float lred[NEXP][4];
    int wave = threadIdx.x >> 6, lane = threadIdx.x & 63;
    if (lane == 0) {
#pragma unroll
        for (int e = 0; e < NEXP; e++) lred[e][wave] = acc[e];
    }
    __syncthreads();
    if (threadIdx.x == 0) {
        float logits[NEXP];
#pragma unroll
        for (int e = 0; e < NEXP; e++)
            logits[e] = lred[e][0] + lred[e][1] + lred[e][2] + lred[e][3];
        int e0 = 0;
        for (int e = 1; e < NEXP; e++) if (logits[e] > logits[e0]) e0 = e;
        int e1 = -1;
        for (int e = 0; e < NEXP; e++) {
            if (e == e0) continue;
            if (e1 < 0 || logits[e] > logits[e1]) e1 = e;
        }
        float l0 = logits[e0], l1 = logits[e1];
        float w0 = 1.f / (1.f + expf(l1 - l0));   // = p0/(p0+p1)
        float w1 = 1.f - w0;
        int p0 = atomicAdd(&counts[e0], 1);
        rowids[e0 * NTOK + p0] = 2 * t;
        rweights[e0 * NTOK + p0] = w0;
        int p1 = atomicAdd(&counts[e1], 1);
        rowids[e1 * NTOK + p1] = 2 * t + 1;
        rweights[e1 * NTOK + p1] = w1;
    }
}

// ---------------- stage A: H[pair] = silu(x W1^T) * (x W3^T)  (bf16 out) ----
// tile: M=128 (gathered pairs), N=64 (ffn cols), BK=32. 4 waves, each 32x64.
__global__ __launch_bounds__(256) void moe_ffn1(
        const float* __restrict__ X, const float* __restrict__ W1,
        const float* __restrict__ W3, const int* __restrict__ counts,
        const int* __restrict__ rowids, unsigned short* __restrict__ H) {
    int bid = blockIdx.x;
    int mtile = bid & 15;
    int ntile = (bid >> 4) % 88;
    int e = bid / (16 * 88);
    int cnt = counts[e];
    if (mtile * 128 >= cnt) return;

    __shared__ unsigned short As[128 * 40];
    __shared__ unsigned short B1s[64 * 40];
    __shared__ unsigned short B3s[64 * 40];
    __shared__ int rlist[128];

    int tid = threadIdx.x;
    if (tid < 128) {
        int idx = mtile * 128 + tid;
        rlist[tid] = (idx < cnt) ? rowids[e * NTOK + idx] : -1;
    }
    __syncthreads();

    const float* w1p = W1 + (size_t)e * FFN * HID + (size_t)(ntile * 64) * HID;
    const float* w3p = W3 + (size_t)e * FFN * HID + (size_t)(ntile * 64) * HID;

    int srow = tid >> 3;           // 0..31
    int scol = (tid & 7) * 4;      // 0,4,...,28
    int wave = tid >> 6, lane = tid & 63;
    int lrow = lane & 15, lquad = lane >> 4;

    f32x4 acc1[2][4], acc3[2][4];
#pragma unroll
    for (int i = 0; i < 2; i++)
#pragma unroll
        for (int j = 0; j < 4; j++) { acc1[i][j] = (f32x4)0.f; acc3[i][j] = (f32x4)0.f; }

    for (int kb = 0; kb < HID; kb += 32) {
        __syncthreads();   // previous iter's frag reads done
        // stage A tile: 128 rows x 32 k, gathered
#pragma unroll
        for (int p = 0; p < 4; p++) {
            int row = p * 32 + srow;
            int rid = rlist[row];
            int tok = (rid >= 0) ? (rid >> 1) : 0;
            float4 v = *(const float4*)(X + (size_t)tok * HID + kb + scol);
            ushort4 s; s.x = f2bf(v.x); s.y = f2bf(v.y); s.z = f2bf(v.z); s.w = f2bf(v.w);
            *(ushort4*)&As[row * 40 + scol] = s;
        }
        // stage B1/B3 tiles: 64 rows x 32 k
#pragma unroll
        for (int p = 0; p < 2; p++) {
            int row = p * 32 + srow;
            float4 v1 = *(const float4*)(w1p + (size_t)row * HID + kb + scol);
            float4 v3 = *(const float4*)(w3p + (size_t)row * HID + kb + scol);
            ushort4 s1; s1.x = f2bf(v1.x); s1.y = f2bf(v1.y); s1.z = f2bf(v1.z); s1.w = f2bf(v1.w);
            ushort4 s3; s3.x = f2bf(v3.x); s3.y = f2bf(v3.y); s3.z = f2bf(v3.z); s3.w = f2bf(v3.w);
            *(ushort4*)&B1s[row * 40 + scol] = s1;
            *(ushort4*)&B3s[row * 40 + scol] = s3;
        }
        __syncthreads();

        bf16x8 af[2];
#pragma unroll
        for (int i = 0; i < 2; i++)
            af[i] = *(const bf16x8*)&As[(wave * 32 + i * 16 + lrow) * 40 + lquad * 8];
        bf16x8 b1f[4], b3f[4];
#pragma unroll
        for (int j = 0; j < 4; j++) {
            b1f[j] = *(const bf16x8*)&B1s[(j * 16 + lrow) * 40 + lquad * 8];
            b3f[j] = *(const bf16x8*)&B3s[(j * 16 + lrow) * 40 + lquad * 8];
        }
#pragma unroll
        for (int i = 0; i < 2; i++)
#pragma unroll
            for (int j = 0; j < 4; j++) {
                acc1[i][j] = __builtin_amdgcn_mfma_f32_16x16x32_bf16(af[i], b1f[j], acc1[i][j], 0, 0, 0);
                acc3[i][j] = __builtin_amdgcn_mfma_f32_16x16x32_bf16(af[i], b3f[j], acc3[i][j], 0, 0, 0);
            }
    }

    int nbase = ntile * 64;
#pragma unroll
    for (int i = 0; i < 2; i++)
#pragma unroll
        for (int j = 0; j < 4; j++)
#pragma unroll
            for (int r = 0; r < 4; r++) {
                int m = wave * 32 + i * 16 + lquad * 4 + r;
                int rid = rlist[m];
                if (rid >= 0) {
                    float a1 = acc1[i][j][r], a3 = acc3[i][j][r];
                    float h = (a1 / (1.f + __expf(-a1))) * a3;   // silu(a1)*a3
                    H[(size_t)rid * FFN + nbase + j * 16 + lrow] = f2bf(h);
                }
            }
}

// ---------------- stage B: out[t] += weight * (H[pair] W2^T) ----------------
// tile: M=128 pairs, N=64 (of 2048), K=5632, BK=32
__global__ __launch_bounds__(256) void moe_ffn2(
        const unsigned short* __restrict__ H, const float* __restrict__ W2,
        const int* __restrict__ counts, const int* __restrict__ rowids,
        const float* __restrict__ rweights, float* __restrict__ Out) {
    int bid = blockIdx.x;
    int mtile = bid & 15;
    int ntile = (bid >> 4) & 31;
    int e = bid >> 9;
    int cnt = counts[e];
    if (mtile * 128 >= cnt) return;

    __shared__ unsigned short As[128 * 40];
    __shared__ unsigned short Bs[64 * 40];
    __shared__ int rlist[128];
    __shared__ float wlist[128];

    int tid = threadIdx.x;
    if (tid < 128) {
        int idx = mtile * 128 + tid;
        rlist[tid] = (idx < cnt) ? rowids[e * NTOK + idx] : -1;
        wlist[tid] = (idx < cnt) ? rweights[e * NTOK + idx] : 0.f;
    }
    __syncthreads();

    const float* w2p = W2 + (size_t)e * HID * FFN + (size_t)(ntile * 64) * FFN;

    int arow = tid >> 2;            // 0..63
    int acol8 = (tid & 3) * 8;      // 0,8,16,24
    int brow = tid >> 3;            // 0..31
    int bcol = (tid & 7) * 4;
    int wave = tid >> 6, lane = tid & 63;
    int lrow = lane & 15, lquad = lane >> 4;

    f32x4 acc[2][4];
#pragma unroll
    for (int i = 0; i < 2; i++)
#pragma unroll
        for (int j = 0; j < 4; j++) acc[i][j] = (f32x4)0.f;

    for (int kb = 0; kb < FFN; kb += 32) {
        __syncthreads();
        // stage A (bf16 H, gathered, raw copy)
#pragma unroll
        for (int p = 0; p < 2; p++) {
            int row = p * 64 + arow;
            int rid = rlist[row];
            int hrow = (rid >= 0) ? rid : 0;
            uint4 hv = *(const uint4*)(H + (size_t)hrow * FFN + kb + acol8);
            *(uint4*)&As[row * 40 + acol8] = hv;
        }
        // stage B (w2, fp32 -> bf16)
#pragma unroll
        for (int p = 0; p < 2; p++) {
            int row = p * 32 + brow;
            float4 v = *(const float4*)(w2p + (size_t)row * FFN + kb + bcol);
            ushort4 s; s.x = f2bf(v.x); s.y = f2bf(v.y); s.z = f2bf(v.z); s.w = f2bf(v.w);
            *(ushort4*)&Bs[row * 40 + bcol] = s;
        }
        __syncthreads();

        bf16x8 af[2];
#pragma unroll
        for (int i = 0; i < 2; i++)
            af[i] = *(const bf16x8*)&As[(wave * 32 + i * 16 + lrow) * 40 + lquad * 8];
        bf16x8 bf[4];
#pragma unroll
        for (int j = 0; j < 4; j++)
            bf[j] = *(const bf16x8*)&Bs[(j * 16 + lrow) * 40 + lquad * 8];
#pragma unroll
        for (int i = 0; i < 2; i++)
#pragma unroll
            for (int j = 0; j < 4; j++)
                acc[i][j] = __builtin_amdgcn_mfma_f32_16x16x32_bf16(af[i], bf[j], acc[i][j], 0, 0, 0);
    }

    int nbase = ntile * 64;
#pragma unroll
    for (int i = 0; i < 2; i++)
#pragma unroll
        for (int j = 0; j < 4; j++)
#pragma unroll
            for (int r = 0; r < 4; r++) {
                int m = wave * 32 + i * 16 + lquad * 4 + r;
                int rid = rlist[m];
                if (rid >= 0) {
                    int t = rid >> 1;
                    int n = nbase + j * 16 + lrow;
                    atomicAdd(&Out[(size_t)t * HID + n], acc[i][j][r] * wlist[m]);
                }
            }
}

// ---------------------------------------------------------------------------
extern "C" void kernel_launch(void* const* d_in, const int* in_sizes, int n_in,
                              void* d_out, int out_size, void* d_ws, size_t ws_size,
                              hipStream_t stream) {
    const float* x  = (const float*)d_in[0];
    const float* wg = (const float*)d_in[1];
    const float* w1 = (const float*)d_in[2];
    const float* w2 = (const float*)d_in[3];
    const float* w3 = (const float*)d_in[4];
    float* out = (float*)d_out;

    char* ws = (char*)d_ws;
    int*   counts   = (int*)ws;                         // 8 ints (256 B reserved)
    int*   rowids   = (int*)(ws + 256);                 // 8*2048 ints = 64 KB
    float* rweights = (float*)(ws + 256 + 65536);       // 64 KB
    unsigned short* H = (unsigned short*)(ws + 131328); // 4096*5632 bf16 = 46 MB

    int n4 = NTOK * HID / 4;
    zero_kernel<<<(n4 + 255) / 256, 256, 0, stream>>>((float4*)out, n4, counts);
    router_kernel<<<NTOK, 256, 0, stream>>>(x, wg, counts, rowids, rweights);
    moe_ffn1<<<NEXP * 88 * 16, 256, 0, stream>>>(x, w1, w3, counts, rowids, H);
    moe_ffn2<<<NEXP * 32 * 16, 256, 0, stream>>>(H, w2, counts, rowids, rweights, out);
}